// Round 5
// baseline (282.608 us; speedup 1.0000x reference)
//
#include <hip/hip_runtime.h>
#include <hip/hip_bf16.h>

// FLoss: mean over i of (1 - output[i, target[i]])^2
// output: [N,2] float32, target: [N] int32 (0/1), result: scalar float32.
//
// History: R1 82us; R2 (MLP) 76; R3 (coalesced) 75; R4 (no atomics) 74.
// Kernel pinned at ~74us (2.7 TB/s effective) insensitive to MLP/coalescing/
// atomics; per-instr, per-line, BW, and latency models ALL falsified; kernel
// counters invisible (poison fills own top-5).
// R5 = DIAGNOSTIC: 3 passes over the data (block-rotated per pass to defeat
// load CSE), scale 1/(3N). Warm passes (LLC-resident, 192MiB<256MiB) tell us
// whether the floor is in the HBM read path (probe ~130us) or in
// issue/fixed overhead (probe ~220us). Also forces floss into top-5 with
// full counters.

#define N_TOTAL 16777216
#define BLOCK 256
#define F4_PER_THREAD 8
#define F4_PER_BLOCK (BLOCK * F4_PER_THREAD)          // 2048 float4 = 4096 rows
#define N_F4 (N_TOTAL / 2)                            // 8388608 float4 in output
#define GRID (N_F4 / F4_PER_BLOCK)                    // 4096 blocks
#define PASSES 3

__global__ __launch_bounds__(BLOCK) void floss_probe_kernel(
    const float4* __restrict__ out4,   // float4 p = rows 2p,2p+1 (cols interleaved)
    const int2*  __restrict__ tgt2,    // int2  p = targets 2p,2p+1
    float* __restrict__ partials)      // [GRID]
{
    const int t = threadIdx.x;
    float acc = 0.0f;

    #pragma unroll 1
    for (int p = 0; p < PASSES; ++p) {
        // rotate block->data mapping per pass: bijection on [0,GRID),
        // different addresses per pass -> compiler cannot CSE pass loads.
        int vb = blockIdx.x + p * 1365;
        if (vb >= GRID) vb -= GRID;
        const int pbase = vb * F4_PER_BLOCK;

        float4 f[F4_PER_THREAD];
        int2   g[F4_PER_THREAD];

        #pragma unroll
        for (int j = 0; j < F4_PER_THREAD; ++j) {
            const int q = pbase + j * BLOCK + t;
            f[j] = out4[q];
            g[j] = tgt2[q];
        }

        #pragma unroll
        for (int j = 0; j < F4_PER_THREAD; ++j) {
            float x0 = g[j].x ? f[j].y : f[j].x;
            float x1 = g[j].y ? f[j].w : f[j].z;
            float d0 = 1.0f - x0, d1 = 1.0f - x1;
            acc += d0 * d0 + d1 * d1;
        }
    }

    // wave-64 butterfly reduce
    #pragma unroll
    for (int off = 32; off > 0; off >>= 1)
        acc += __shfl_down(acc, off, 64);

    __shared__ float smem[BLOCK / 64];
    const int lane = threadIdx.x & 63;
    const int wave = threadIdx.x >> 6;
    if (lane == 0) smem[wave] = acc;
    __syncthreads();

    if (threadIdx.x == 0) {
        float s = 0.0f;
        #pragma unroll
        for (int w = 0; w < BLOCK / 64; ++w) s += smem[w];
        partials[blockIdx.x] = s;      // plain store, disjoint addresses
    }
}

__global__ __launch_bounds__(BLOCK) void floss_final_kernel(
    const float4* __restrict__ partials4,   // GRID/4 = 1024 float4
    float* __restrict__ result)
{
    const int t = threadIdx.x;
    float acc = 0.0f;
    #pragma unroll
    for (int j = 0; j < GRID / 4 / BLOCK; ++j) {     // 4 float4 per thread
        float4 p = partials4[j * BLOCK + t];
        acc += p.x + p.y + p.z + p.w;
    }

    #pragma unroll
    for (int off = 32; off > 0; off >>= 1)
        acc += __shfl_down(acc, off, 64);

    __shared__ float smem[BLOCK / 64];
    const int lane = threadIdx.x & 63;
    const int wave = threadIdx.x >> 6;
    if (lane == 0) smem[wave] = acc;
    __syncthreads();

    if (threadIdx.x == 0) {
        float s = 0.0f;
        #pragma unroll
        for (int w = 0; w < BLOCK / 64; ++w) s += smem[w];
        // 3 passes each summed the full dataset -> mean = s / (3N)
        *result = s * (1.0f / ((float)PASSES * (float)N_TOTAL));
    }
}

extern "C" void kernel_launch(void* const* d_in, const int* in_sizes, int n_in,
                              void* d_out, int out_size, void* d_ws, size_t ws_size,
                              hipStream_t stream) {
    const float4* out4 = (const float4*)d_in[0];
    const int2*   tgt2 = (const int2*)d_in[1];
    float* partials = (float*)d_ws;          // 4096 floats = 16 KiB of scratch
    float* result = (float*)d_out;

    floss_probe_kernel<<<GRID, BLOCK, 0, stream>>>(out4, tgt2, partials);
    floss_final_kernel<<<1, BLOCK, 0, stream>>>((const float4*)partials, result);
}

// Round 6
// 213.132 us; speedup vs baseline: 1.3260x; 1.3260x over previous
//
#include <hip/hip_runtime.h>
#include <hip/hip_bf16.h>

// FLoss: mean over i of (1 - output[i, target[i]])^2
// output: [N,2] float32, target: [N] int32 (0/1), result: scalar float32.
//
// History: R1 82us; R2 MLP 76; R3 coalesced 75; R4 no-atomics 74.
// R5 probe (3-pass): cold pass 74us, warm LLC passes 26.5us (7.3 TB/s) ->
// kernel structure exonerated; floor is cold/HBM-miss servicing only.
// ~half of inputs are LLC-resident at launch (poison fill evicts the rest).
// R6: (1) REVERSED traversal - read most-recently-written (LLC-resident)
// tail first, overlapping the harness's residual write drain; HBM-resident
// head read later against drained HBM. (2) non-temporal loads - single-pass
// streaming data, skip allocation churn on miss (hits unaffected).

#define N_TOTAL 16777216
#define BLOCK 256
#define F4_PER_THREAD 8
#define F4_PER_BLOCK (BLOCK * F4_PER_THREAD)          // 2048 float4 = 4096 rows
#define N_F4 (N_TOTAL / 2)                            // 8388608 float4 in output
#define GRID (N_F4 / F4_PER_BLOCK)                    // 4096 blocks, one pass

typedef float vfloat4 __attribute__((ext_vector_type(4)));
typedef int   vint2   __attribute__((ext_vector_type(2)));

__global__ __launch_bounds__(BLOCK) void floss_partial_kernel(
    const vfloat4* __restrict__ out4,   // float4 p = rows 2p,2p+1 (cols interleaved)
    const vint2*  __restrict__ tgt2,    // int2  p = targets 2p,2p+1
    float* __restrict__ partials)       // [GRID]
{
    const int t = threadIdx.x;
    // reversed: highest addresses (most recently restored -> LLC-resident) first
    const int vb = GRID - 1 - blockIdx.x;
    const int pbase = vb * F4_PER_BLOCK;

    vfloat4 f[F4_PER_THREAD];
    vint2   g[F4_PER_THREAD];

    // 16 independent, fully-coalesced, non-temporal loads before any use.
    #pragma unroll
    for (int j = 0; j < F4_PER_THREAD; ++j) {
        const int p = pbase + j * BLOCK + t;
        f[j] = __builtin_nontemporal_load(&out4[p]);
        g[j] = __builtin_nontemporal_load(&tgt2[p]);
    }

    float acc = 0.0f;
    #pragma unroll
    for (int j = 0; j < F4_PER_THREAD; ++j) {
        float x0 = g[j].x ? f[j].y : f[j].x;
        float x1 = g[j].y ? f[j].w : f[j].z;
        float d0 = 1.0f - x0, d1 = 1.0f - x1;
        acc += d0 * d0 + d1 * d1;
    }

    // wave-64 butterfly reduce
    #pragma unroll
    for (int off = 32; off > 0; off >>= 1)
        acc += __shfl_down(acc, off, 64);

    __shared__ float smem[BLOCK / 64];
    const int lane = threadIdx.x & 63;
    const int wave = threadIdx.x >> 6;
    if (lane == 0) smem[wave] = acc;
    __syncthreads();

    if (threadIdx.x == 0) {
        float s = 0.0f;
        #pragma unroll
        for (int w = 0; w < BLOCK / 64; ++w) s += smem[w];
        partials[blockIdx.x] = s;      // plain store, disjoint addresses
    }
}

__global__ __launch_bounds__(BLOCK) void floss_final_kernel(
    const vfloat4* __restrict__ partials4,   // GRID/4 = 1024 float4
    float* __restrict__ result)
{
    const int t = threadIdx.x;
    float acc = 0.0f;
    #pragma unroll
    for (int j = 0; j < GRID / 4 / BLOCK; ++j) {     // 4 float4 per thread
        vfloat4 p = partials4[j * BLOCK + t];
        acc += p.x + p.y + p.z + p.w;
    }

    #pragma unroll
    for (int off = 32; off > 0; off >>= 1)
        acc += __shfl_down(acc, off, 64);

    __shared__ float smem[BLOCK / 64];
    const int lane = threadIdx.x & 63;
    const int wave = threadIdx.x >> 6;
    if (lane == 0) smem[wave] = acc;
    __syncthreads();

    if (threadIdx.x == 0) {
        float s = 0.0f;
        #pragma unroll
        for (int w = 0; w < BLOCK / 64; ++w) s += smem[w];
        *result = s * (1.0f / (float)N_TOTAL);   // unconditional write
    }
}

extern "C" void kernel_launch(void* const* d_in, const int* in_sizes, int n_in,
                              void* d_out, int out_size, void* d_ws, size_t ws_size,
                              hipStream_t stream) {
    const vfloat4* out4 = (const vfloat4*)d_in[0];
    const vint2*   tgt2 = (const vint2*)d_in[1];
    float* partials = (float*)d_ws;          // 4096 floats = 16 KiB of scratch
    float* result = (float*)d_out;

    floss_partial_kernel<<<GRID, BLOCK, 0, stream>>>(out4, tgt2, partials);
    floss_final_kernel<<<1, BLOCK, 0, stream>>>((const vfloat4*)partials, result);
}

// Round 7
// 212.458 us; speedup vs baseline: 1.3302x; 1.0032x over previous
//
#include <hip/hip_runtime.h>
#include <hip/hip_bf16.h>

// FLoss: mean over i of (1 - output[i, target[i]])^2
// output: [N,2] float32, target: [N] int32 (0/1), result: scalar float32.
//
// History: R1 82us; R2 MLP 76; R3 coalesced 75; R4 no-atomics 74;
// R5 probe: warm-LLC passes run 7.3 TB/s (structure exonerated; floor is
// cold-miss servicing); R6 reversed+nt: kernel ~57us (bench 229.6->213.1).
// LLC at launch holds ~half of d_in (restore streams 384MiB through 256MiB
// LLC), interleaved with HBM-resident lines.
// R7: keep nt; replace tail-first ordering with a bijective block SCATTER
// (vb = blockIdx*1365 mod 4096) so every co-resident cohort mixes
// LLC-resident and HBM-resident work -> the two tiers are drained in
// PARALLEL (max(t_LLC,t_HBM)) instead of serially (sum). Also ablates
// whether R6's win was nt or ordering.

#define N_TOTAL 16777216
#define BLOCK 256
#define F4_PER_THREAD 8
#define F4_PER_BLOCK (BLOCK * F4_PER_THREAD)          // 2048 float4 = 4096 rows
#define N_F4 (N_TOTAL / 2)                            // 8388608 float4 in output
#define GRID (N_F4 / F4_PER_BLOCK)                    // 4096 blocks, one pass

typedef float vfloat4 __attribute__((ext_vector_type(4)));
typedef int   vint2   __attribute__((ext_vector_type(2)));

__global__ __launch_bounds__(BLOCK) void floss_partial_kernel(
    const vfloat4* __restrict__ out4,   // float4 p = rows 2p,2p+1 (cols interleaved)
    const vint2*  __restrict__ tgt2,    // int2  p = targets 2p,2p+1
    float* __restrict__ partials)       // [GRID]
{
    const int t = threadIdx.x;
    // bijective scatter over [0,4096): consecutive launch-order blocks land
    // 1365*stride apart -> each co-resident cohort covers the whole address
    // range uniformly (LLC-resident + HBM-resident mixed).
    const int vb = (blockIdx.x * 1365) & (GRID - 1);
    const int pbase = vb * F4_PER_BLOCK;

    vfloat4 f[F4_PER_THREAD];
    vint2   g[F4_PER_THREAD];

    // 16 independent, fully-coalesced, non-temporal loads before any use.
    #pragma unroll
    for (int j = 0; j < F4_PER_THREAD; ++j) {
        const int p = pbase + j * BLOCK + t;
        f[j] = __builtin_nontemporal_load(&out4[p]);
        g[j] = __builtin_nontemporal_load(&tgt2[p]);
    }

    float acc = 0.0f;
    #pragma unroll
    for (int j = 0; j < F4_PER_THREAD; ++j) {
        float x0 = g[j].x ? f[j].y : f[j].x;
        float x1 = g[j].y ? f[j].w : f[j].z;
        float d0 = 1.0f - x0, d1 = 1.0f - x1;
        acc += d0 * d0 + d1 * d1;
    }

    // wave-64 butterfly reduce
    #pragma unroll
    for (int off = 32; off > 0; off >>= 1)
        acc += __shfl_down(acc, off, 64);

    __shared__ float smem[BLOCK / 64];
    const int lane = threadIdx.x & 63;
    const int wave = threadIdx.x >> 6;
    if (lane == 0) smem[wave] = acc;
    __syncthreads();

    if (threadIdx.x == 0) {
        float s = 0.0f;
        #pragma unroll
        for (int w = 0; w < BLOCK / 64; ++w) s += smem[w];
        partials[blockIdx.x] = s;      // plain store, disjoint addresses
    }
}

__global__ __launch_bounds__(BLOCK) void floss_final_kernel(
    const vfloat4* __restrict__ partials4,   // GRID/4 = 1024 float4
    float* __restrict__ result)
{
    const int t = threadIdx.x;
    float acc = 0.0f;
    #pragma unroll
    for (int j = 0; j < GRID / 4 / BLOCK; ++j) {     // 4 float4 per thread
        vfloat4 p = partials4[j * BLOCK + t];
        acc += p.x + p.y + p.z + p.w;
    }

    #pragma unroll
    for (int off = 32; off > 0; off >>= 1)
        acc += __shfl_down(acc, off, 64);

    __shared__ float smem[BLOCK / 64];
    const int lane = threadIdx.x & 63;
    const int wave = threadIdx.x >> 6;
    if (lane == 0) smem[wave] = acc;
    __syncthreads();

    if (threadIdx.x == 0) {
        float s = 0.0f;
        #pragma unroll
        for (int w = 0; w < BLOCK / 64; ++w) s += smem[w];
        *result = s * (1.0f / (float)N_TOTAL);   // unconditional write
    }
}

extern "C" void kernel_launch(void* const* d_in, const int* in_sizes, int n_in,
                              void* d_out, int out_size, void* d_ws, size_t ws_size,
                              hipStream_t stream) {
    const vfloat4* out4 = (const vfloat4*)d_in[0];
    const vint2*   tgt2 = (const vint2*)d_in[1];
    float* partials = (float*)d_ws;          // 4096 floats = 16 KiB of scratch
    float* result = (float*)d_out;

    floss_partial_kernel<<<GRID, BLOCK, 0, stream>>>(out4, tgt2, partials);
    floss_final_kernel<<<1, BLOCK, 0, stream>>>((const vfloat4*)partials, result);
}